// Round 2
// baseline (409.963 us; speedup 1.0000x reference)
//
#include <hip/hip_runtime.h>
#include <math.h>

// ---------------------------------------------------------------------------
// NTM cell. ALL I/O fp32 (per reference setup_inputs dtypes); bf16 MFMA used
// internally for the LSTM GEMM (test tolerance is bf16-grade).
// B=4096, IN=64, U=256, N=128, W=64, OUT=64, NPH=70, P=268, K_lstm=384.
// Pipeline: k_transpose -> k_lstm (MFMA) -> k_params -> k_addr -> k_out
// ---------------------------------------------------------------------------

typedef unsigned short u16;
typedef __attribute__((ext_vector_type(8))) __bf16 bf16x8;
typedef __attribute__((ext_vector_type(8))) unsigned short u16x8;
typedef __attribute__((ext_vector_type(4))) float f32x4;

#define DI __device__ __forceinline__

static constexpr int Bn = 4096;

// output element offsets (order: out, read_vec, w_read, w_write, M_new, h_new, c_new)
static constexpr size_t OFF_OUT = 0;
static constexpr size_t OFF_RV  = (size_t)Bn * 64;
static constexpr size_t OFF_WR  = OFF_RV + (size_t)Bn * 64;
static constexpr size_t OFF_WW  = OFF_WR + (size_t)Bn * 128;
static constexpr size_t OFF_M   = OFF_WW + (size_t)Bn * 128;
static constexpr size_t OFF_H   = OFF_M + (size_t)Bn * 128 * 64;
static constexpr size_t OFF_C   = OFF_H + (size_t)Bn * 256;

// ws byte offsets
static constexpr size_t WS_WT = 0;                             // bf16 1024x384
static constexpr size_t WS_H  = 786432;                        // f32 4096x256
static constexpr size_t WS_P  = WS_H + (size_t)Bn * 256 * 4;   // f32 4096x268
static constexpr size_t WS_RV = WS_P + (size_t)Bn * 268 * 4;   // f32 4096x64

DI u16 f2b(float f) {
  unsigned int u = __float_as_uint(f);
  unsigned int r = (u + 0x7fffu + ((u >> 16) & 1u)) >> 16;  // RNE
  return (u16)r;
}
DI float sigf(float x) { return 1.f / (1.f + expf(-x)); }

DI void gld16(const void* g, void* l) {
  __builtin_amdgcn_global_load_lds(
      (const __attribute__((address_space(1))) unsigned int*)g,
      (__attribute__((address_space(3))) unsigned int*)l, 16, 0, 0);
}

DI float wsum(float v) {
  v += __shfl_xor(v, 32, 64); v += __shfl_xor(v, 16, 64);
  v += __shfl_xor(v, 8, 64);  v += __shfl_xor(v, 4, 64);
  v += __shfl_xor(v, 2, 64);  v += __shfl_xor(v, 1, 64);
  return v;
}
DI float wmax(float v) {
  v = fmaxf(v, __shfl_xor(v, 32, 64)); v = fmaxf(v, __shfl_xor(v, 16, 64));
  v = fmaxf(v, __shfl_xor(v, 8, 64));  v = fmaxf(v, __shfl_xor(v, 4, 64));
  v = fmaxf(v, __shfl_xor(v, 2, 64));  v = fmaxf(v, __shfl_xor(v, 1, 64));
  return v;
}

// ---------------------------------------------------------------------------
// K0: Wt[c][k] = bf16( k<128 ? W_k[k][c] : W_r[k-128][c] )   c<1024, k<384
// ---------------------------------------------------------------------------
__global__ __launch_bounds__(256) void k_transpose(
    const float* __restrict__ W_k, const float* __restrict__ W_r, u16* __restrict__ Wt)
{
  __shared__ float tile[64][65];
  const int c0 = blockIdx.x * 64, k0 = blockIdx.y * 64;
  const int t = threadIdx.x;
  {
    const int r2 = t >> 4, cc = (t & 15) * 4;
#pragma unroll
    for (int rr = 0; rr < 4; rr++) {
      int row = rr * 16 + r2;  // k-row within block
      const float* src = (k0 < 128) ? (W_k + (size_t)(k0 + row) * 1024)
                                    : (W_r + (size_t)(k0 - 128 + row) * 1024);
      float4 v = *(const float4*)(src + c0 + cc);
      tile[row][cc + 0] = v.x; tile[row][cc + 1] = v.y;
      tile[row][cc + 2] = v.z; tile[row][cc + 3] = v.w;
    }
  }
  __syncthreads();
  const int wr = t >> 2, wc0 = (t & 3) * 16;
  u16* dst = Wt + (size_t)(c0 + wr) * 384 + k0 + wc0;
#pragma unroll
  for (int j = 0; j < 16; j++) dst[j] = f2b(tile[wc0 + j][wr]);
}

// ---------------------------------------------------------------------------
// K1: fused LSTM. z = [x|rv0|h0] @ [W_k;W_r] + b -> gates -> h_new, c_new.
// Block: 64 batch rows x (4 gates x 32 u-cols). A: fp32 global -> bf16 LDS
// (ds_write_b128, XOR chunk swizzle). B: bf16 Wt via global_load_lds.
// ---------------------------------------------------------------------------
__global__ __launch_bounds__(256) void k_lstm(
    const float* __restrict__ x, const float* __restrict__ rv0, const float* __restrict__ h0,
    const float* __restrict__ c0, const float* __restrict__ b_lstm, const u16* __restrict__ Wt,
    float* __restrict__ h_ws, float* __restrict__ out)
{
  __shared__ __align__(16) u16 As[64 * 32];   // 4 KB
  __shared__ __align__(16) u16 Bs[128 * 32];  // 8 KB
  const int t = threadIdx.x;
  const int wv = t >> 6, lane = t & 63;
  const int m0 = blockIdx.x * 64, u0 = blockIdx.y * 32;
  const int lane15 = lane & 15, quad = lane >> 4;

  f32x4 acc[8];
#pragma unroll
  for (int i = 0; i < 8; i++) acc[i] = (f32x4){0.f, 0.f, 0.f, 0.f};

  const int mrow = wv * 16 + lane15;
  const int aChunk = mrow * 4 + (quad ^ (mrow & 3));

  for (int kstep = 0; kstep < 12; ++kstep) {
    const int k0 = kstep * 32;
    const float* srcA; int ldA, colA;
    if (k0 < 64)       { srcA = x;   ldA = 64;  colA = k0; }
    else if (k0 < 128) { srcA = rv0; ldA = 64;  colA = k0 - 64; }
    else               { srcA = h0;  ldA = 256; colA = k0 - 128; }
    {
      const int m = t >> 2, kq = t & 3;
      const float* ap = srcA + (size_t)(m0 + m) * ldA + colA + kq * 8;
      float4 v0 = *(const float4*)ap;
      float4 v1 = *(const float4*)(ap + 4);
      u16x8 pk;
      pk[0] = f2b(v0.x); pk[1] = f2b(v0.y); pk[2] = f2b(v0.z); pk[3] = f2b(v0.w);
      pk[4] = f2b(v1.x); pk[5] = f2b(v1.y); pk[6] = f2b(v1.z); pk[7] = f2b(v1.w);
      *(u16x8*)(As + (m * 4 + (kq ^ (m & 3))) * 8) = pk;
    }
#pragma unroll
    for (int r = 0; r < 2; ++r) {
      int lin = r * 256 + t;
      int cl = lin >> 2, kq = (lin & 3) ^ (cl & 3);
      int cg = (cl >> 5) * 256 + u0 + (cl & 31);  // gate-stripe gather
      gld16(Wt + (size_t)cg * 384 + k0 + kq * 8, Bs + lin * 8);
    }
    __syncthreads();  // drains lgkm (ds_write) + vm (global_load_lds)
    bf16x8 a = *(const bf16x8*)(As + aChunk * 8);
#pragma unroll
    for (int nt = 0; nt < 8; ++nt) {
      int crow = nt * 16 + lane15;
      bf16x8 bfr = *(const bf16x8*)(Bs + (crow * 4 + (quad ^ (crow & 3))) * 8);
      acc[nt] = __builtin_amdgcn_mfma_f32_16x16x32_bf16(a, bfr, acc[nt], 0, 0, 0);
    }
    __syncthreads();
  }

  // acc[g*2+up]: gate g, col u0+up*16+lane15, rows quad*4+r (within wave's 16-row slab)
#pragma unroll
  for (int up = 0; up < 2; ++up) {
    const int u = u0 + up * 16 + lane15;
    const float bi  = b_lstm[u];
    const float bff = b_lstm[256 + u];
    const float bg  = b_lstm[512 + u];
    const float bo  = b_lstm[768 + u];
#pragma unroll
    for (int r = 0; r < 4; ++r) {
      const int brow = m0 + wv * 16 + quad * 4 + r;
      float zi = acc[0 + up][r] + bi;
      float zf = acc[2 + up][r] + bff;
      float zg = acc[4 + up][r] + bg;
      float zo = acc[6 + up][r] + bo;
      float cold = c0[(size_t)brow * 256 + u];
      float cn = sigf(zf) * cold + sigf(zi) * tanhf(zg);
      float hn = sigf(zo) * tanhf(cn);
      h_ws[(size_t)brow * 256 + u] = hn;
      out[OFF_H + (size_t)brow * 256 + u] = hn;
      out[OFF_C + (size_t)brow * 256 + u] = cn;
    }
  }
}

// ---------------------------------------------------------------------------
// K2: params = clip(h_new @ W_p + b_p, +-20). 16 rows/block, fp32 VALU.
// ---------------------------------------------------------------------------
__global__ __launch_bounds__(320) void k_params(
    const float* __restrict__ h_ws, const float* __restrict__ W_p,
    const float* __restrict__ b_p, float* __restrict__ p_ws)
{
  __shared__ float hs[16][256];  // 16 KB
  const int b0 = blockIdx.x * 16, t = threadIdx.x;
#pragma unroll
  for (int i = 0; i < 13; i++) {
    int lin = i * 320 + t;
    if (lin < 4096) hs[lin >> 8][lin & 255] = h_ws[(size_t)b0 * 256 + lin];
  }
  __syncthreads();
  if (t < 268) {
    float acc[16];
#pragma unroll
    for (int r = 0; r < 16; r++) acc[r] = 0.f;
    for (int k4 = 0; k4 < 64; k4++) {
      float wp0 = W_p[(k4 * 4 + 0) * 268 + t];
      float wp1 = W_p[(k4 * 4 + 1) * 268 + t];
      float wp2 = W_p[(k4 * 4 + 2) * 268 + t];
      float wp3 = W_p[(k4 * 4 + 3) * 268 + t];
#pragma unroll
      for (int r = 0; r < 16; r++) {
        f32x4 h4 = *(const f32x4*)&hs[r][k4 * 4];
        acc[r] += h4[0] * wp0 + h4[1] * wp1 + h4[2] * wp2 + h4[3] * wp3;
      }
    }
    float bp = b_p[t];
#pragma unroll
    for (int r = 0; r < 16; r++) {
      float v = fminf(fmaxf(acc[r] + bp, -20.f), 20.f);
      p_ws[(size_t)(b0 + r) * 268 + t] = v;
    }
  }
}

// ---------------------------------------------------------------------------
// K3: addressing + read_vec + M_new. One block per batch row. M (32 KB fp32)
// staged in LDS via global_load_lds with a 16B-granule XOR swizzle applied on
// the GLOBAL address side (gld writes LDS at wave-uniform base + lane*16, so
// padding is not possible; the swizzle makes both the column-parallel phase 2
// and row-parallel phase 4 bank-conflict-free).
// ---------------------------------------------------------------------------
__global__ __launch_bounds__(256) void k_addr(
    const float* __restrict__ M, const float* __restrict__ w0p, const float* __restrict__ w1p,
    const float* __restrict__ params, float* __restrict__ rv_ws, float* __restrict__ out)
{
  __shared__ __align__(16) float Ms[8192];  // 32 KB, swizzled
  __shared__ float kn[2][64];
  __shared__ float scal[2][6];              // beta, g, s0, s1, s2, gamma
  __shared__ float ksim[2][128];
  __shared__ float wgs[2][128];
  __shared__ float wprev[2][128];
  __shared__ float wfin[2][128];
  __shared__ float red1[2][2], red2[2][2], red3[2][2];
  __shared__ float rvpart[4][64];

  const int b = blockIdx.x, t = threadIdx.x;
  const int wv = t >> 6, lane = t & 63;

  // stage M: LDS chunk lin <- global 16B granule (n, cf = (lin&15) ^ (n&15))
#pragma unroll
  for (int i = 0; i < 8; i++) {
    int lin = i * 256 + t;
    int n = lin >> 4, cf = (lin & 15) ^ (n & 15);
    gld16(M + (size_t)b * 8192 + n * 64 + cf * 4, Ms + lin * 4);
  }

  const float* p = params + (size_t)b * 268;
  if (t < 128) {
    const int h = wv, j = lane;
    float kv = tanhf(p[h * 70 + j]);
    float ssk = wsum(kv * kv);
    kn[h][j] = kv * rsqrtf(fmaxf(ssk, 1e-12f));
    if (j == 0) {
      float beta = log1pf(expf(p[h * 70 + 64]));
      float g = sigf(p[h * 70 + 65]);
      float s0 = p[h * 70 + 66], s1 = p[h * 70 + 67], s2 = p[h * 70 + 68];
      float mx = fmaxf(s0, fmaxf(s1, s2));
      float e0 = expf(s0 - mx), e1 = expf(s1 - mx), e2 = expf(s2 - mx);
      float inv = 1.f / (e0 + e1 + e2);
      scal[h][0] = beta; scal[h][1] = g;
      scal[h][2] = e0 * inv; scal[h][3] = e1 * inv; scal[h][4] = e2 * inv;
      scal[h][5] = log1pf(expf(p[h * 70 + 69])) + 1.f;
    }
  } else {
    int idx = t & 127;
    wprev[0][idx] = w0p[(size_t)b * 128 + idx];
    wprev[1][idx] = w1p[(size_t)b * 128 + idx];
  }
  __syncthreads();  // Ms + kn + scal + wprev ready

  // Phase 2: per-slot norm + similarity (2 threads per n, halves of W)
  {
    const int n = t >> 1, hf = t & 1;
    float ssm = 0.f, dr = 0.f, dw = 0.f;
#pragma unroll
    for (int c4 = 0; c4 < 8; c4++) {
      int cf = hf * 8 + c4;
      f32x4 m4 = *(const f32x4*)(Ms + (n * 16 + (cf ^ (n & 15))) * 4);
#pragma unroll
      for (int j = 0; j < 4; j++) {
        float mv = m4[j];
        int kidx = cf * 4 + j;
        ssm += mv * mv;
        dr += kn[0][kidx] * mv;
        dw += kn[1][kidx] * mv;
      }
    }
    ssm += __shfl_xor(ssm, 1, 64);
    dr  += __shfl_xor(dr, 1, 64);
    dw  += __shfl_xor(dw, 1, 64);
    if (hf == 0) {
      float inv = rsqrtf(fmaxf(ssm, 1e-12f));
      ksim[0][n] = -dr * inv;   // negative cosine similarity (faithful to ref)
      ksim[1][n] = -dw * inv;
    }
  }
  __syncthreads();

  // Phase 3: softmax -> interpolate -> shift -> sharpen (2 heads in parallel)
  {
    const int h = t >> 7, nn = t & 127, sub = (t >> 6) & 1;
    float beta = scal[h][0], g = scal[h][1];
    float s0 = scal[h][2], s1 = scal[h][3], s2 = scal[h][4], gamma = scal[h][5];
    float v = beta * ksim[h][nn];
    float m1 = wmax(v);
    if (lane == 0) red1[h][sub] = m1;
    __syncthreads();
    float mx = fmaxf(red1[h][0], red1[h][1]);
    float e = expf(v - mx);
    float sm = wsum(e);
    if (lane == 0) red2[h][sub] = sm;
    __syncthreads();
    float wc = e / (red2[h][0] + red2[h][1]);
    float wgv = g * wc + (1.f - g) * wprev[h][nn];
    wgs[h][nn] = wgv;
    __syncthreads();
    float w_ = s0 * wgv + s1 * wgs[h][(nn + 127) & 127] + s2 * wgs[h][(nn + 1) & 127];
    float wsh = powf(w_, gamma);
    float s3 = wsum(wsh);
    if (lane == 0) red3[h][sub] = s3;
    __syncthreads();
    float wf = wsh / (red3[h][0] + red3[h][1]);
    wfin[h][nn] = wf;
    out[(h ? OFF_WW : OFF_WR) + (size_t)b * 128 + nn] = wf;
  }
  __syncthreads();

  // Phase 4: read_vec + M_new from the LDS copy of M
  {
    const int w = lane, grp = wv;
    float er = sigf(p[140 + w]);
    float ad = tanhf(p[204 + w]);
    float rvp = 0.f;
    float* mout = out + OFF_M + (size_t)b * 8192;
    for (int n2 = grp; n2 < 128; n2 += 4) {
      float mv = Ms[(n2 * 16 + ((w >> 2) ^ (n2 & 15))) * 4 + (w & 3)];
      float wrn = wfin[0][n2];
      float wwn = wfin[1][n2];
      rvp += wrn * mv;
      mout[n2 * 64 + w] = mv * (1.f - wwn * er) + wwn * ad;
    }
    rvpart[grp][w] = rvp;
  }
  __syncthreads();
  if (t < 64) {
    float rv = rvpart[0][t] + rvpart[1][t] + rvpart[2][t] + rvpart[3][t];
    out[OFF_RV + (size_t)b * 64 + t] = rv;
    rv_ws[(size_t)b * 64 + t] = rv;
  }
}

// ---------------------------------------------------------------------------
// K4: out = clip([h_new, read_vec] @ W_o + b_o, +-20). 32 rows/block.
// ---------------------------------------------------------------------------
__global__ __launch_bounds__(256) void k_out(
    const float* __restrict__ h_ws, const float* __restrict__ rv_ws,
    const float* __restrict__ W_o, const float* __restrict__ b_o, float* __restrict__ out)
{
  __shared__ float in_s[32][320];  // 40 KB
  const int b0 = blockIdx.x * 32, t = threadIdx.x;
  for (int r = 0; r < 32; r++) {
    in_s[r][t] = h_ws[(size_t)(b0 + r) * 256 + t];
    if (t < 64) in_s[r][256 + t] = rv_ws[(size_t)(b0 + r) * 64 + t];
  }
  __syncthreads();
  const int c = t & 63, rg = t >> 6;  // 4 row-groups of 8
  float acc[8] = {0, 0, 0, 0, 0, 0, 0, 0};
#pragma unroll 4
  for (int k = 0; k < 320; k++) {
    float wo = W_o[k * 64 + c];
#pragma unroll
    for (int r = 0; r < 8; r++) acc[r] += in_s[rg * 8 + r][k] * wo;
  }
  float bo = b_o[c];
#pragma unroll
  for (int r = 0; r < 8; r++) {
    float v = fminf(fmaxf(acc[r] + bo, -20.f), 20.f);
    out[OFF_OUT + (size_t)(b0 + rg * 8 + r) * 64 + c] = v;
  }
}

// ---------------------------------------------------------------------------
extern "C" void kernel_launch(void* const* d_in, const int* in_sizes, int n_in,
                              void* d_out, int out_size, void* d_ws, size_t ws_size,
                              hipStream_t stream)
{
  const float* x   = (const float*)d_in[0];
  const float* h0  = (const float*)d_in[1];
  const float* c0  = (const float*)d_in[2];
  const float* rv0 = (const float*)d_in[3];
  const float* w0p = (const float*)d_in[4];
  const float* w1p = (const float*)d_in[5];
  const float* M   = (const float*)d_in[6];
  const float* W_k = (const float*)d_in[7];
  const float* W_r = (const float*)d_in[8];
  const float* b_l = (const float*)d_in[9];
  const float* W_p = (const float*)d_in[10];
  const float* b_p = (const float*)d_in[11];
  const float* W_o = (const float*)d_in[12];
  const float* b_o = (const float*)d_in[13];
  float* out = (float*)d_out;
  char* ws = (char*)d_ws;
  u16*   Wt    = (u16*)(ws + WS_WT);
  float* h_ws  = (float*)(ws + WS_H);
  float* p_ws  = (float*)(ws + WS_P);
  float* rv_ws = (float*)(ws + WS_RV);

  k_transpose<<<dim3(16, 6), 256, 0, stream>>>(W_k, W_r, Wt);
  k_lstm<<<dim3(64, 8), 256, 0, stream>>>(x, rv0, h0, c0, b_l, Wt, h_ws, out);
  k_params<<<256, 320, 0, stream>>>(h_ws, W_p, b_p, p_ws);
  k_addr<<<4096, 256, 0, stream>>>(M, w0p, w1p, p_ws, rv_ws, out);
  k_out<<<128, 256, 0, stream>>>(h_ws, rv_ws, W_o, b_o, out);
}